// Round 3
// baseline (932.438 us; speedup 1.0000x reference)
//
#include <hip/hip_runtime.h>
#include <stdint.h>

#define BB 8
#define CC 16
#define HH 96
#define WW 96
#define HID 128
#define HW (HH*WW)            // 9216
#define CHW (CC*HW)           // 147456
#define NPIX (BB*HW)          // 73728
#define STEPS 16

// ---------------- Threefry-2x32 (JAX-compatible, 20 rounds) ----------------
__host__ __device__ inline void threefry2x32(uint32_t k0, uint32_t k1,
                                             uint32_t x0, uint32_t x1,
                                             uint32_t& o0, uint32_t& o1) {
  const uint32_t ks2 = k0 ^ k1 ^ 0x1BD11BDAu;
  uint32_t v0 = x0 + k0, v1 = x1 + k1;
#define RL(v, r) (((v) << (r)) | ((v) >> (32 - (r))))
#define RND(r) { v0 += v1; v1 = RL(v1, r); v1 ^= v0; }
  RND(13) RND(15) RND(26) RND(6)   v0 += k1;  v1 += ks2 + 1u;
  RND(17) RND(29) RND(16) RND(24)  v0 += ks2; v1 += k0 + 2u;
  RND(13) RND(15) RND(26) RND(6)   v0 += k0;  v1 += k1 + 3u;
  RND(17) RND(29) RND(16) RND(24)  v0 += k1;  v1 += ks2 + 4u;
  RND(13) RND(15) RND(26) RND(6)   v0 += ks2; v1 += k0 + 5u;
#undef RND
#undef RL
  o0 = v0; o1 = v1;
}

// fire: jax.random.uniform(key_i,(B,1,H,W)) < 0.5 ; partitionable threefry:
// bits[j] = x0 ^ x1 of threefry(key_i, (0, j)); u<0.5 <=> top bit clear.
__device__ inline float fire_val(uint32_t ka, uint32_t kb, uint32_t j) {
  uint32_t r0, r1;
  threefry2x32(ka, kb, 0u, j, r0, r1);
  return ((r0 ^ r1) & 0x80000000u) ? 0.0f : 1.0f;
}

// ---------------- w2 transpose: (16,128) -> (128,16) ----------------
__global__ void transp_w2(const float* __restrict__ w2, float* __restrict__ w2t) {
  int i = threadIdx.x + blockIdx.x * blockDim.x;
  if (i < CC * HID) {
    int o = i / HID, k = i - o * HID;
    w2t[k * CC + o] = w2[i];
  }
}

// ---------------- Kernel A: perception + MLP + fire -> raw ----------------
// block = 512 threads = 8 waves; all waves share the same 64 pixels (lane =
// pixel), each wave owns 16 of 128 hidden rows -> 9216 waves total (9/SIMD
// launched) to hide s_load weight latency. LDS reduction combines the 8
// partial update vectors.
__global__ __launch_bounds__(512) void ca_update(
    const float* __restrict__ xcur, const float* __restrict__ w1,
    const float* __restrict__ b1,   const float* __restrict__ w2t,
    const float* __restrict__ b2,   float* __restrict__ raw,
    uint32_t ka, uint32_t kb)
{
  __shared__ float red[8][CC][64];   // [eighth][channel][pixel-lane] : 32 KiB
  __shared__ float fire_lds[64];
  const int tid  = threadIdx.x;
  const int lane = tid & 63;
  const int q    = __builtin_amdgcn_readfirstlane(tid >> 6);  // wave-uniform
  const int P    = blockIdx.x * 64 + lane;
  const int b    = P / HW;
  const int rem  = P - b * HW;
  const int h    = rem / WW;
  const int w    = rem - h * WW;

  if (q == 0) fire_lds[lane] = fire_val(ka, kb, (uint32_t)P);  // once per pixel

  // ---- perception: p = [x, grad_x, grad_y] (sobel/8, correlation, zero-pad)
  float p[3 * CC];
  const float* xb = xcur + b * CHW + h * WW + w;
  const bool hm = (h > 0), hp = (h < HH - 1), wm = (w > 0), wp = (w < WW - 1);
#pragma unroll
  for (int c = 0; c < CC; ++c) {
    const float* xc = xb + c * HW;
    float v00 = (hm && wm) ? xc[-WW - 1] : 0.f;
    float v01 = (hm      ) ? xc[-WW    ] : 0.f;
    float v02 = (hm && wp) ? xc[-WW + 1] : 0.f;
    float v10 = (wm      ) ? xc[-1]      : 0.f;
    float v11 =              xc[0];
    float v12 = (wp      ) ? xc[1]       : 0.f;
    float v20 = (hp && wm) ? xc[ WW - 1] : 0.f;
    float v21 = (hp      ) ? xc[ WW    ] : 0.f;
    float v22 = (hp && wp) ? xc[ WW + 1] : 0.f;
    p[c]          = v11;
    p[CC + c]     = ((v02 - v00) + 2.f * (v12 - v10) + (v22 - v20)) * 0.125f;
    p[2 * CC + c] = ((v20 - v00) + 2.f * (v21 - v01) + (v22 - v02)) * 0.125f;
  }

  float upd[CC];
#pragma unroll
  for (int k = 0; k < CC; ++k) upd[k] = 0.f;

  const int row0 = q * 16;
#pragma unroll
  for (int o = 0; o < 16; ++o) {
    const int row = row0 + o;
    const float* wr = w1 + row * 48;     // wave-uniform -> s_load broadcast
    float a0 = b1[row], a1 = 0.f, a2 = 0.f, a3 = 0.f;
#pragma unroll
    for (int c = 0; c < 12; ++c) {
      a0 = fmaf(wr[c     ], p[c     ], a0);
      a1 = fmaf(wr[c + 12], p[c + 12], a1);
      a2 = fmaf(wr[c + 24], p[c + 24], a2);
      a3 = fmaf(wr[c + 36], p[c + 36], a3);
    }
    float y = (a0 + a1) + (a2 + a3);
    y = fmaxf(y, 0.f);                   // relu
    const float* w2r = w2t + row * CC;   // wave-uniform -> s_load broadcast
#pragma unroll
    for (int k = 0; k < CC; ++k) upd[k] = fmaf(w2r[k], y, upd[k]);
  }

  // ---- cross-wave reduction via LDS, lane-contiguous (no bank conflicts)
#pragma unroll
  for (int k = 0; k < CC; ++k) red[q][k][lane] = upd[k];
  __syncthreads();

  const float fire = fire_lds[lane];
  const int c0 = q * 2;                  // this wave finalizes 2 channels
#pragma unroll
  for (int cc = 0; cc < 2; ++cc) {
    const int c = c0 + cc;
    float s = ((red[0][c][lane] + red[1][c][lane]) +
               (red[2][c][lane] + red[3][c][lane])) +
              ((red[4][c][lane] + red[5][c][lane]) +
               (red[6][c][lane] + red[7][c][lane])) + b2[c];
    const int idx = b * CHW + c * HW + h * WW + w;
    raw[idx] = xcur[idx] + s * fire;     // xn (pre-life, pre-clip)
  }
}

// ---------------- Kernel B: life mask (3x3 maxpool on ch3) + clip ----------
__global__ __launch_bounds__(256) void ca_life(
    const float* __restrict__ xcur, const float* __restrict__ raw,
    float* __restrict__ xnext)
{
  const int P = blockIdx.x * 256 + threadIdx.x;
  const int b = P / HW;
  const int rem = P - b * HW;
  const int h = rem / WW;
  const int w = rem - h * WW;
  const bool hm = (h > 0), hp = (h < HH - 1), wm = (w > 0), wp = (w < WW - 1);
  const int base3 = b * CHW + 3 * HW + h * WW + w;

  float m1, m2;
  {
    const float* xc = xcur + base3;
    const float* xr = raw + base3;
    m1 = xc[0]; m2 = xr[0];
    if (hm) {
      m1 = fmaxf(m1, xc[-WW]); m2 = fmaxf(m2, xr[-WW]);
      if (wm) { m1 = fmaxf(m1, xc[-WW-1]); m2 = fmaxf(m2, xr[-WW-1]); }
      if (wp) { m1 = fmaxf(m1, xc[-WW+1]); m2 = fmaxf(m2, xr[-WW+1]); }
    }
    if (wm) { m1 = fmaxf(m1, xc[-1]); m2 = fmaxf(m2, xr[-1]); }
    if (wp) { m1 = fmaxf(m1, xc[ 1]); m2 = fmaxf(m2, xr[ 1]); }
    if (hp) {
      m1 = fmaxf(m1, xc[WW]); m2 = fmaxf(m2, xr[WW]);
      if (wm) { m1 = fmaxf(m1, xc[WW-1]); m2 = fmaxf(m2, xr[WW-1]); }
      if (wp) { m1 = fmaxf(m1, xc[WW+1]); m2 = fmaxf(m2, xr[WW+1]); }
    }
  }
  const float life = ((m1 > 0.1f) && (m2 > 0.1f)) ? 1.f : 0.f;

  const int base = b * CHW + h * WW + w;
#pragma unroll
  for (int c = 0; c < CC; ++c) {
    float v = raw[base + c * HW] * life;
    v = fminf(fmaxf(v, -10.f), 10.f);
    xnext[base + c * HW] = v;
  }
}

// ---------------- launcher ----------------
extern "C" void kernel_launch(void* const* d_in, const int* in_sizes, int n_in,
                              void* d_out, int out_size, void* d_ws, size_t ws_size,
                              hipStream_t stream) {
  const float* x  = (const float*)d_in[0];
  const float* w1 = (const float*)d_in[1];
  const float* b1 = (const float*)d_in[2];
  const float* w2 = (const float*)d_in[3];
  const float* b2 = (const float*)d_in[4];
  float* out = (float*)d_out;

  char* ws = (char*)d_ws;
  const size_t BUF = (size_t)NPIX * CC * sizeof(float);   // 4,718,592 B
  float* bufA   = (float*)(ws);
  float* bufRaw = (float*)(ws + BUF);
  float* w2t    = (float*)(ws + 2 * BUF);                 // 8 KiB

  hipLaunchKernelGGL(transp_w2, dim3(8), dim3(256), 0, stream, w2, w2t);

  const float* cur = x;
  for (int i = 0; i < STEPS; ++i) {
    uint32_t ka, kb;
    threefry2x32(0u, 42u, 0u, (uint32_t)i, ka, kb);       // fold_in(key(42), i)
    float* next = (i & 1) ? out : bufA;                   // step 15 (odd) -> out
    hipLaunchKernelGGL(ca_update, dim3(NPIX / 64), dim3(512), 0, stream,
                       cur, w1, b1, w2t, b2, bufRaw, ka, kb);
    hipLaunchKernelGGL(ca_life, dim3(NPIX / 256), dim3(256), 0, stream,
                       cur, bufRaw, next);
    cur = next;
  }
  (void)in_sizes; (void)n_in; (void)out_size; (void)ws_size;
}

// Round 4
// 610.251 us; speedup vs baseline: 1.5280x; 1.5280x over previous
//
#include <hip/hip_runtime.h>
#include <stdint.h>

#define BB 8
#define CC 16
#define HH 96
#define WW 96
#define HID 128
#define HW (HH*WW)            // 9216
#define CHW (CC*HW)           // 147456
#define NPIX (BB*HW)          // 73728
#define STEPS 16

// ---------------- Threefry-2x32 (JAX-compatible, 20 rounds) ----------------
__host__ __device__ inline void threefry2x32(uint32_t k0, uint32_t k1,
                                             uint32_t x0, uint32_t x1,
                                             uint32_t& o0, uint32_t& o1) {
  const uint32_t ks2 = k0 ^ k1 ^ 0x1BD11BDAu;
  uint32_t v0 = x0 + k0, v1 = x1 + k1;
#define RL(v, r) (((v) << (r)) | ((v) >> (32 - (r))))
#define RND(r) { v0 += v1; v1 = RL(v1, r); v1 ^= v0; }
  RND(13) RND(15) RND(26) RND(6)   v0 += k1;  v1 += ks2 + 1u;
  RND(17) RND(29) RND(16) RND(24)  v0 += ks2; v1 += k0 + 2u;
  RND(13) RND(15) RND(26) RND(6)   v0 += k0;  v1 += k1 + 3u;
  RND(17) RND(29) RND(16) RND(24)  v0 += k1;  v1 += ks2 + 4u;
  RND(13) RND(15) RND(26) RND(6)   v0 += ks2; v1 += k0 + 5u;
#undef RND
#undef RL
  o0 = v0; o1 = v1;
}

// fire: jax.random.uniform(key_i,(B,1,H,W)) < 0.5 ; partitionable threefry:
// bits[j] = x0 ^ x1 of threefry(key_i, (0, j)); u<0.5 <=> top bit clear.
__device__ inline float fire_val(uint32_t ka, uint32_t kb, uint32_t j) {
  uint32_t r0, r1;
  threefry2x32(ka, kb, 0u, j, r0, r1);
  return ((r0 ^ r1) & 0x80000000u) ? 0.0f : 1.0f;
}

// ---------------- w2 transpose: (16,128) -> (128,16) ----------------
__global__ void transp_w2(const float* __restrict__ w2, float* __restrict__ w2t) {
  int i = threadIdx.x + blockIdx.x * blockDim.x;
  if (i < CC * HID) {
    int o = i / HID, k = i - o * HID;
    w2t[k * CC + o] = w2[i];
  }
}

// ---------------- Kernel A: perception + MLP + fire -> raw ----------------
// block = 256 threads = 4 waves; all waves share the same 64 pixels (lane =
// pixel), each wave owns 32 of 128 hidden rows; LDS reduction combines.
// XCD swizzle: batch = blockIdx.x % 8 (grid 1152 = 8 batches x 144) so each
// XCD's L2 holds only its batch slice (590 KB << 4 MiB) -> L2-resident state.
__global__ __launch_bounds__(256) void ca_update(
    const float* __restrict__ xcur, const float* __restrict__ w1,
    const float* __restrict__ b1,   const float* __restrict__ w2t,
    const float* __restrict__ b2,   float* __restrict__ raw,
    uint32_t ka, uint32_t kb)
{
  __shared__ float red[4][CC][64];   // [quarter][channel][pixel-lane] : 16 KiB
  __shared__ float fire_lds[64];
  const int tid  = threadIdx.x;
  const int lane = tid & 63;
  const int q    = __builtin_amdgcn_readfirstlane(tid >> 6);  // wave-uniform
  const int b    = blockIdx.x & 7;          // batch == XCD (round-robin)
  const int seg  = blockIdx.x >> 3;         // 0..143 within batch
  const int rem  = seg * 64 + lane;         // pixel within image
  const int h    = rem / WW;
  const int w    = rem - h * WW;
  const int P    = b * HW + rem;            // global pixel id (fire index)

  if (q == 0) fire_lds[lane] = fire_val(ka, kb, (uint32_t)P);  // once per pixel

  // ---- perception: p = [x, grad_x, grad_y] (sobel/8, correlation, zero-pad)
  float p[3 * CC];
  const float* xb = xcur + b * CHW + h * WW + w;
  const bool hm = (h > 0), hp = (h < HH - 1), wm = (w > 0), wp = (w < WW - 1);
#pragma unroll
  for (int c = 0; c < CC; ++c) {
    const float* xc = xb + c * HW;
    float v00 = (hm && wm) ? xc[-WW - 1] : 0.f;
    float v01 = (hm      ) ? xc[-WW    ] : 0.f;
    float v02 = (hm && wp) ? xc[-WW + 1] : 0.f;
    float v10 = (wm      ) ? xc[-1]      : 0.f;
    float v11 =              xc[0];
    float v12 = (wp      ) ? xc[1]       : 0.f;
    float v20 = (hp && wm) ? xc[ WW - 1] : 0.f;
    float v21 = (hp      ) ? xc[ WW    ] : 0.f;
    float v22 = (hp && wp) ? xc[ WW + 1] : 0.f;
    p[c]          = v11;
    p[CC + c]     = ((v02 - v00) + 2.f * (v12 - v10) + (v22 - v20)) * 0.125f;
    p[2 * CC + c] = ((v20 - v00) + 2.f * (v21 - v01) + (v22 - v02)) * 0.125f;
  }

  float upd[CC];
#pragma unroll
  for (int k = 0; k < CC; ++k) upd[k] = 0.f;

  const int row0 = q * 32;
#pragma unroll 2
  for (int o = 0; o < 32; ++o) {
    const int row = row0 + o;
    const float* wr = w1 + row * 48;     // wave-uniform -> s_load broadcast
    float a0 = b1[row], a1 = 0.f, a2 = 0.f, a3 = 0.f;
#pragma unroll
    for (int c = 0; c < 12; ++c) {
      a0 = fmaf(wr[c     ], p[c     ], a0);
      a1 = fmaf(wr[c + 12], p[c + 12], a1);
      a2 = fmaf(wr[c + 24], p[c + 24], a2);
      a3 = fmaf(wr[c + 36], p[c + 36], a3);
    }
    float y = (a0 + a1) + (a2 + a3);
    y = fmaxf(y, 0.f);                   // relu
    const float* w2r = w2t + row * CC;   // wave-uniform -> s_load broadcast
#pragma unroll
    for (int k = 0; k < CC; ++k) upd[k] = fmaf(w2r[k], y, upd[k]);
  }

  // ---- cross-wave reduction via LDS, lane-contiguous (no bank conflicts)
#pragma unroll
  for (int k = 0; k < CC; ++k) red[q][k][lane] = upd[k];
  __syncthreads();

  const float fire = fire_lds[lane];
  const int c0 = q * 4;                  // this wave finalizes 4 channels
#pragma unroll
  for (int cc = 0; cc < 4; ++cc) {
    const int c = c0 + cc;
    float s = (red[0][c][lane] + red[1][c][lane]) +
              (red[2][c][lane] + red[3][c][lane]) + b2[c];
    const int idx = b * CHW + c * HW + h * WW + w;
    raw[idx] = p[c] + s * fire;          // p[c] == xcur center (reuse, no re-read)
  }
}

// ---------------- Kernel B: life mask (3x3 maxpool on ch3) + clip ----------
// grid 288 = 8 batches x 36; batch = blockIdx.x % 8 (same XCD partitioning).
__global__ __launch_bounds__(256) void ca_life(
    const float* __restrict__ xcur, const float* __restrict__ raw,
    float* __restrict__ xnext)
{
  const int b   = blockIdx.x & 7;
  const int rem = (blockIdx.x >> 3) * 256 + threadIdx.x;
  const int h = rem / WW;
  const int w = rem - h * WW;
  const bool hm = (h > 0), hp = (h < HH - 1), wm = (w > 0), wp = (w < WW - 1);
  const int base3 = b * CHW + 3 * HW + h * WW + w;

  float m1, m2;
  {
    const float* xc = xcur + base3;
    const float* xr = raw + base3;
    m1 = xc[0]; m2 = xr[0];
    if (hm) {
      m1 = fmaxf(m1, xc[-WW]); m2 = fmaxf(m2, xr[-WW]);
      if (wm) { m1 = fmaxf(m1, xc[-WW-1]); m2 = fmaxf(m2, xr[-WW-1]); }
      if (wp) { m1 = fmaxf(m1, xc[-WW+1]); m2 = fmaxf(m2, xr[-WW+1]); }
    }
    if (wm) { m1 = fmaxf(m1, xc[-1]); m2 = fmaxf(m2, xr[-1]); }
    if (wp) { m1 = fmaxf(m1, xc[ 1]); m2 = fmaxf(m2, xr[ 1]); }
    if (hp) {
      m1 = fmaxf(m1, xc[WW]); m2 = fmaxf(m2, xr[WW]);
      if (wm) { m1 = fmaxf(m1, xc[WW-1]); m2 = fmaxf(m2, xr[WW-1]); }
      if (wp) { m1 = fmaxf(m1, xc[WW+1]); m2 = fmaxf(m2, xr[WW+1]); }
    }
  }
  const float life = ((m1 > 0.1f) && (m2 > 0.1f)) ? 1.f : 0.f;

  const int base = b * CHW + h * WW + w;
#pragma unroll
  for (int c = 0; c < CC; ++c) {
    float v = raw[base + c * HW] * life;
    v = fminf(fmaxf(v, -10.f), 10.f);
    xnext[base + c * HW] = v;
  }
}

// ---------------- launcher ----------------
extern "C" void kernel_launch(void* const* d_in, const int* in_sizes, int n_in,
                              void* d_out, int out_size, void* d_ws, size_t ws_size,
                              hipStream_t stream) {
  const float* x  = (const float*)d_in[0];
  const float* w1 = (const float*)d_in[1];
  const float* b1 = (const float*)d_in[2];
  const float* w2 = (const float*)d_in[3];
  const float* b2 = (const float*)d_in[4];
  float* out = (float*)d_out;

  char* ws = (char*)d_ws;
  const size_t BUF = (size_t)NPIX * CC * sizeof(float);   // 4,718,592 B
  float* bufA   = (float*)(ws);
  float* bufRaw = (float*)(ws + BUF);
  float* w2t    = (float*)(ws + 2 * BUF);                 // 8 KiB

  hipLaunchKernelGGL(transp_w2, dim3(8), dim3(256), 0, stream, w2, w2t);

  const float* cur = x;
  for (int i = 0; i < STEPS; ++i) {
    uint32_t ka, kb;
    threefry2x32(0u, 42u, 0u, (uint32_t)i, ka, kb);       // fold_in(key(42), i)
    float* next = (i & 1) ? out : bufA;                   // step 15 (odd) -> out
    hipLaunchKernelGGL(ca_update, dim3(NPIX / 64), dim3(256), 0, stream,
                       cur, w1, b1, w2t, b2, bufRaw, ka, kb);
    hipLaunchKernelGGL(ca_life, dim3(NPIX / 256), dim3(256), 0, stream,
                       cur, bufRaw, next);
    cur = next;
  }
  (void)in_sizes; (void)n_in; (void)out_size; (void)ws_size;
}

// Round 5
// 440.891 us; speedup vs baseline: 2.1149x; 1.3841x over previous
//
#include <hip/hip_runtime.h>
#include <stdint.h>

#define BB 8
#define CC 16
#define HH 96
#define WW 96
#define HID 128
#define HW (HH*WW)            // 9216
#define CHW (CC*HW)           // 147456
#define NPIX (BB*HW)          // 73728
#define STEPS 16

// ---------------- Threefry-2x32 (JAX-compatible, 20 rounds) ----------------
__host__ __device__ inline void threefry2x32(uint32_t k0, uint32_t k1,
                                             uint32_t x0, uint32_t x1,
                                             uint32_t& o0, uint32_t& o1) {
  const uint32_t ks2 = k0 ^ k1 ^ 0x1BD11BDAu;
  uint32_t v0 = x0 + k0, v1 = x1 + k1;
#define RL(v, r) (((v) << (r)) | ((v) >> (32 - (r))))
#define RND(r) { v0 += v1; v1 = RL(v1, r); v1 ^= v0; }
  RND(13) RND(15) RND(26) RND(6)   v0 += k1;  v1 += ks2 + 1u;
  RND(17) RND(29) RND(16) RND(24)  v0 += ks2; v1 += k0 + 2u;
  RND(13) RND(15) RND(26) RND(6)   v0 += k0;  v1 += k1 + 3u;
  RND(17) RND(29) RND(16) RND(24)  v0 += k1;  v1 += ks2 + 4u;
  RND(13) RND(15) RND(26) RND(6)   v0 += ks2; v1 += k0 + 5u;
#undef RND
#undef RL
  o0 = v0; o1 = v1;
}

// fire: jax.random.uniform(key_i,(B,1,H,W)) < 0.5 ; partitionable threefry:
// bits[j] = x0 ^ x1 of threefry(key_i, (0, j)); u<0.5 <=> top bit clear.
__device__ inline float fire_val(uint32_t ka, uint32_t kb, uint32_t j) {
  uint32_t r0, r1;
  threefry2x32(ka, kb, 0u, j, r0, r1);
  return ((r0 ^ r1) & 0x80000000u) ? 0.0f : 1.0f;
}

// ---------------- w2 transpose: (16,128) -> (128,16) ----------------
__global__ void transp_w2(const float* __restrict__ w2, float* __restrict__ w2t) {
  int i = threadIdx.x + blockIdx.x * blockDim.x;
  if (i < CC * HID) {
    int o = i / HID, k = i - o * HID;
    w2t[k * CC + o] = w2[i];
  }
}

// ---------------- Kernel A: perception + MLP + fire -> raw, prelife --------
// block = 256 threads = 4 waves over the SAME 64 pixels (lane = pixel).
// Phase 1 (cooperative): wave q computes perception for channels {q,q+4,q+8,
// q+12} -> p_lds[48][64] (feature-major, lane-contiguous: conflict-free).
// The c==3 window also yields pre_life's 3x3 max -> prelife buffer.
// Phase 2: each wave owns 32 of 128 hidden rows; features read from LDS with
// STATIC indices only (no runtime-indexed register arrays -> no scratch).
// XCD swizzle: batch = blockIdx.x % 8 (grid 1152 = 8 x 144) -> L2-resident.
__global__ __launch_bounds__(256) void ca_update(
    const float* __restrict__ xcur, const float* __restrict__ w1,
    const float* __restrict__ b1,   const float* __restrict__ w2t,
    const float* __restrict__ b2,   float* __restrict__ raw,
    float* __restrict__ prelife,    uint32_t ka, uint32_t kb)
{
  __shared__ float p_lds[3 * CC][64];  // 12 KiB
  __shared__ float red[4][CC][64];     // 16 KiB
  __shared__ float fire_lds[64];
  const int tid  = threadIdx.x;
  const int lane = tid & 63;
  const int q    = __builtin_amdgcn_readfirstlane(tid >> 6);  // wave-uniform
  const int b    = blockIdx.x & 7;          // batch == XCD slot
  const int seg  = blockIdx.x >> 3;         // 0..143 within batch
  const int rem  = seg * 64 + lane;         // pixel within image
  const int h    = rem / WW;
  const int w    = rem - h * WW;
  const int P    = b * HW + rem;            // global pixel id

  if (q == 0) fire_lds[lane] = fire_val(ka, kb, (uint32_t)P);  // once per pixel

  // ---- Phase 1: cooperative perception (each wave: 4 of 16 channels)
  const float* xb = xcur + b * CHW + h * WW + w;
  const bool hm = (h > 0), hp = (h < HH - 1), wm = (w > 0), wp = (w < WW - 1);
#pragma unroll
  for (int cc = 0; cc < 4; ++cc) {
    const int c = q + cc * 4;                // wave-uniform
    const float* xc = xb + c * HW;
    float v00 = (hm && wm) ? xc[-WW - 1] : 0.f;
    float v01 = (hm      ) ? xc[-WW    ] : 0.f;
    float v02 = (hm && wp) ? xc[-WW + 1] : 0.f;
    float v10 = (wm      ) ? xc[-1]      : 0.f;
    float v11 =              xc[0];
    float v12 = (wp      ) ? xc[1]       : 0.f;
    float v20 = (hp && wm) ? xc[ WW - 1] : 0.f;
    float v21 = (hp      ) ? xc[ WW    ] : 0.f;
    float v22 = (hp && wp) ? xc[ WW + 1] : 0.f;
    p_lds[c][lane]          = v11;
    p_lds[CC + c][lane]     = ((v02 - v00) + 2.f * (v12 - v10) + (v22 - v20)) * 0.125f;
    p_lds[2 * CC + c][lane] = ((v20 - v00) + 2.f * (v21 - v01) + (v22 - v02)) * 0.125f;
    if (c == 3) {
      // pre_life max (0-pad instead of -inf is safe: 0 < 0.1 threshold)
      float m1 = fmaxf(fmaxf(fmaxf(v00, v01), fmaxf(v02, v10)),
                       fmaxf(fmaxf(v11, v12), fmaxf(fmaxf(v20, v21), v22)));
      prelife[P] = m1;
    }
  }
  __syncthreads();

  // ---- Phase 2: MLP. Static-index feature fetch from LDS.
  float p[3 * CC];
#pragma unroll
  for (int f = 0; f < 3 * CC; ++f) p[f] = p_lds[f][lane];

  float upd[CC];
#pragma unroll
  for (int k = 0; k < CC; ++k) upd[k] = 0.f;

  const int row0 = q * 32;
#pragma unroll 2
  for (int o = 0; o < 32; ++o) {
    const int row = row0 + o;
    const float* wr = w1 + row * 48;     // wave-uniform -> s_load broadcast
    float a0 = b1[row], a1 = 0.f, a2 = 0.f, a3 = 0.f;
#pragma unroll
    for (int c = 0; c < 12; ++c) {
      a0 = fmaf(wr[c     ], p[c     ], a0);
      a1 = fmaf(wr[c + 12], p[c + 12], a1);
      a2 = fmaf(wr[c + 24], p[c + 24], a2);
      a3 = fmaf(wr[c + 36], p[c + 36], a3);
    }
    float y = (a0 + a1) + (a2 + a3);
    y = fmaxf(y, 0.f);                   // relu
    const float* w2r = w2t + row * CC;   // wave-uniform -> s_load broadcast
#pragma unroll
    for (int k = 0; k < CC; ++k) upd[k] = fmaf(w2r[k], y, upd[k]);
  }

  // ---- cross-wave reduction via LDS, lane-contiguous (no bank conflicts)
#pragma unroll
  for (int k = 0; k < CC; ++k) red[q][k][lane] = upd[k];
  __syncthreads();

  const float fire = fire_lds[lane];
  const int c0 = q * 4;                  // this wave finalizes 4 channels
#pragma unroll
  for (int cc = 0; cc < 4; ++cc) {
    const int c = c0 + cc;
    float s = (red[0][c][lane] + red[1][c][lane]) +
              (red[2][c][lane] + red[3][c][lane]) + b2[c];
    const int idx = b * CHW + c * HW + h * WW + w;
    // center value from LDS (runtime c is fine for LDS, NOT for reg arrays)
    raw[idx] = p_lds[c][lane] + s * fire;
  }
}

// ---------------- Kernel B: life mask + clip ------------------------------
// grid 1152 = 8 batches x 144; block = 64 pixels x 4 channel-groups.
// pre_life comes precomputed from ca_update; post_life maxpool on raw ch3.
__global__ __launch_bounds__(256) void ca_life(
    const float* __restrict__ prelife, const float* __restrict__ raw,
    float* __restrict__ xnext)
{
  const int lane = threadIdx.x & 63;
  const int g    = threadIdx.x >> 6;        // channel quad 0..3
  const int b    = blockIdx.x & 7;
  const int seg  = blockIdx.x >> 3;
  const int rem  = seg * 64 + lane;
  const int h = rem / WW;
  const int w = rem - h * WW;
  const int P = b * HW + rem;
  const bool hm = (h > 0), hp = (h < HH - 1), wm = (w > 0), wp = (w < WW - 1);

  float m2;
  {
    const float* xr = raw + b * CHW + 3 * HW + h * WW + w;
    m2 = xr[0];
    if (hm) {
      m2 = fmaxf(m2, xr[-WW]);
      if (wm) m2 = fmaxf(m2, xr[-WW - 1]);
      if (wp) m2 = fmaxf(m2, xr[-WW + 1]);
    }
    if (wm) m2 = fmaxf(m2, xr[-1]);
    if (wp) m2 = fmaxf(m2, xr[ 1]);
    if (hp) {
      m2 = fmaxf(m2, xr[WW]);
      if (wm) m2 = fmaxf(m2, xr[WW - 1]);
      if (wp) m2 = fmaxf(m2, xr[WW + 1]);
    }
  }
  const float life = ((prelife[P] > 0.1f) && (m2 > 0.1f)) ? 1.f : 0.f;

  const int base = b * CHW + h * WW + w;
#pragma unroll
  for (int cc = 0; cc < 4; ++cc) {
    const int c = g + cc * 4;               // wave-uniform
    float v = raw[base + c * HW] * life;
    v = fminf(fmaxf(v, -10.f), 10.f);
    xnext[base + c * HW] = v;
  }
}

// ---------------- launcher ----------------
extern "C" void kernel_launch(void* const* d_in, const int* in_sizes, int n_in,
                              void* d_out, int out_size, void* d_ws, size_t ws_size,
                              hipStream_t stream) {
  const float* x  = (const float*)d_in[0];
  const float* w1 = (const float*)d_in[1];
  const float* b1 = (const float*)d_in[2];
  const float* w2 = (const float*)d_in[3];
  const float* b2 = (const float*)d_in[4];
  float* out = (float*)d_out;

  char* ws = (char*)d_ws;
  const size_t BUF = (size_t)NPIX * CC * sizeof(float);   // 4,718,592 B
  float* bufA    = (float*)(ws);
  float* bufRaw  = (float*)(ws + BUF);
  float* w2t     = (float*)(ws + 2 * BUF);                // 8 KiB
  float* prelife = (float*)(ws + 2 * BUF + 8192);         // NPIX floats

  hipLaunchKernelGGL(transp_w2, dim3(8), dim3(256), 0, stream, w2, w2t);

  const float* cur = x;
  for (int i = 0; i < STEPS; ++i) {
    uint32_t ka, kb;
    threefry2x32(0u, 42u, 0u, (uint32_t)i, ka, kb);       // fold_in(key(42), i)
    float* next = (i & 1) ? out : bufA;                   // step 15 (odd) -> out
    hipLaunchKernelGGL(ca_update, dim3(NPIX / 64), dim3(256), 0, stream,
                       cur, w1, b1, w2t, b2, bufRaw, prelife, ka, kb);
    hipLaunchKernelGGL(ca_life, dim3(NPIX / 64), dim3(256), 0, stream,
                       prelife, bufRaw, next);
    cur = next;
  }
  (void)in_sizes; (void)n_in; (void)out_size; (void)ws_size;
}

// Round 6
// 433.234 us; speedup vs baseline: 2.1523x; 1.0177x over previous
//
#include <hip/hip_runtime.h>
#include <stdint.h>

#define BB 8
#define CC 16
#define HH 96
#define WW 96
#define HID 128
#define HW (HH*WW)            // 9216
#define CHW (CC*HW)           // 147456
#define NPIX (BB*HW)          // 73728
#define STEPS 16

// ---------------- Threefry-2x32 (JAX-compatible, 20 rounds) ----------------
__host__ __device__ inline void threefry2x32(uint32_t k0, uint32_t k1,
                                             uint32_t x0, uint32_t x1,
                                             uint32_t& o0, uint32_t& o1) {
  const uint32_t ks2 = k0 ^ k1 ^ 0x1BD11BDAu;
  uint32_t v0 = x0 + k0, v1 = x1 + k1;
#define RL(v, r) (((v) << (r)) | ((v) >> (32 - (r))))
#define RND(r) { v0 += v1; v1 = RL(v1, r); v1 ^= v0; }
  RND(13) RND(15) RND(26) RND(6)   v0 += k1;  v1 += ks2 + 1u;
  RND(17) RND(29) RND(16) RND(24)  v0 += ks2; v1 += k0 + 2u;
  RND(13) RND(15) RND(26) RND(6)   v0 += k0;  v1 += k1 + 3u;
  RND(17) RND(29) RND(16) RND(24)  v0 += k1;  v1 += ks2 + 4u;
  RND(13) RND(15) RND(26) RND(6)   v0 += ks2; v1 += k0 + 5u;
#undef RND
#undef RL
  o0 = v0; o1 = v1;
}

// fire: jax.random.uniform(key_i,(B,1,H,W)) < 0.5 ; partitionable threefry:
// bits[j] = x0 ^ x1 of threefry(key_i, (0, j)); u<0.5 <=> top bit clear.
__device__ inline float fire_val(uint32_t ka, uint32_t kb, uint32_t j) {
  uint32_t r0, r1;
  threefry2x32(ka, kb, 0u, j, r0, r1);
  return ((r0 ^ r1) & 0x80000000u) ? 0.0f : 1.0f;
}

// ---------------- w2 transpose: (16,128) -> (128,16) ----------------
__global__ void transp_w2(const float* __restrict__ w2, float* __restrict__ w2t) {
  int i = threadIdx.x + blockIdx.x * blockDim.x;
  if (i < CC * HID) {
    int o = i / HID, k = i - o * HID;
    w2t[k * CC + o] = w2[i];
  }
}

// ---------------- Fused step kernel -----------------------------------------
// Step-shifted fusion: F_i rebuilds x_i = clip(raw_{i-1} * life_{i-1}) in LDS
// (10x10 halo'd tile), then perception + MLP + fire -> raw_i, prelife_i.
// F_0 (apply_life=0) loads x_0 directly. Block = 256 thr = 4 waves over an
// 8x8 interior tile (lane = pixel); wave q owns 32 of 128 hidden rows.
// Grid 1152 = 8 batches x 144 tiles; batch = blockIdx.x % 8 (XCD-local L2).
__global__ __launch_bounds__(256) void ca_fused(
    const float* __restrict__ src,     // x0 (step 0) or raw_{i-1}
    const float* __restrict__ plprev,  // prelife_{i-1} (ignored when step 0)
    const float* __restrict__ w1,  const float* __restrict__ b1,
    const float* __restrict__ w2t, const float* __restrict__ b2,
    float* __restrict__ rawout, float* __restrict__ plout,
    uint32_t ka, uint32_t kb, int apply_life)
{
  __shared__ float xt[CC][100];      // x_i tile, 10x10 halo'd   6.4 KiB
  __shared__ float raw3[144];        // raw ch3, 12x12           0.6 KiB
  __shared__ float life_l[100];
  __shared__ float fire_lds[64];
  __shared__ float ovl[4 * CC * 64]; // overlay: p_lds(12K) / red(16K)
#define P_LDS(f, l) ovl[(f) * 64 + (l)]
#define RED(qq, k, l) ovl[(((qq) * CC) + (k)) * 64 + (l)]

  const int tid  = threadIdx.x;
  const int lane = tid & 63;
  const int q    = __builtin_amdgcn_readfirstlane(tid >> 6);  // wave-uniform
  const int b    = blockIdx.x & 7;           // batch == XCD slot
  const int t    = blockIdx.x >> 3;          // tile 0..143
  const int h0   = (t / 12) * 8, w0 = (t % 12) * 8;
  const int py   = lane >> 3, px = lane & 7; // interior pixel coords
  const int h    = h0 + py, w = w0 + px;
  const int P    = b * HW + h * WW + w;      // global pixel id

  if (q == 0) fire_lds[lane] = fire_val(ka, kb, (uint32_t)P);

  // ---- A1: raw ch3 12x12 (only needed when applying life)
  if (apply_life) {
    for (int i = tid; i < 144; i += 256) {
      const int r = i / 12, c = i - r * 12;
      const int hh = h0 - 2 + r, ww = w0 - 2 + c;
      float v = 0.f;
      if (hh >= 0 && hh < HH && ww >= 0 && ww < WW)
        v = src[b * CHW + 3 * HW + hh * WW + ww];
      raw3[i] = v;
    }
    __syncthreads();
    // ---- A2: life on the 10x10 halo region
    for (int i = tid; i < 100; i += 256) {
      const int r = i / 10, c = i - r * 10;
      float m = raw3[r * 12 + c];
      m = fmaxf(m, raw3[r * 12 + c + 1]); m = fmaxf(m, raw3[r * 12 + c + 2]);
      m = fmaxf(m, raw3[(r + 1) * 12 + c]);     m = fmaxf(m, raw3[(r + 1) * 12 + c + 1]);
      m = fmaxf(m, raw3[(r + 1) * 12 + c + 2]); m = fmaxf(m, raw3[(r + 2) * 12 + c]);
      m = fmaxf(m, raw3[(r + 2) * 12 + c + 1]); m = fmaxf(m, raw3[(r + 2) * 12 + c + 2]);
      const int hh = h0 - 1 + r, ww = w0 - 1 + c;
      float pl = 0.f;
      if (hh >= 0 && hh < HH && ww >= 0 && ww < WW)
        pl = plprev[b * HW + hh * WW + ww];
      life_l[i] = ((m > 0.1f) && (pl > 0.1f)) ? 1.f : 0.f;
    }
    __syncthreads();
  }

  // ---- A3: build x_i tile (10x10 x 16ch), zero outside image
  for (int i = tid; i < CC * 100; i += 256) {
    const int ch = i / 100, rc = i - ch * 100;
    const int r = rc / 10, c = rc - r * 10;
    const int hh = h0 - 1 + r, ww = w0 - 1 + c;
    float v = 0.f;
    if (hh >= 0 && hh < HH && ww >= 0 && ww < WW) {
      v = src[b * CHW + ch * HW + hh * WW + ww];
      if (apply_life) {
        v *= life_l[rc];
        v = fminf(fmaxf(v, -10.f), 10.f);
      }
    }
    xt[ch][rc] = v;
  }
  __syncthreads();

  // ---- A4 (wave 0): prelife_i = 3x3 max of x_i ch3, interior pixels
  if (q == 0) {
    const int ctr = py * 10 + px;  // window rows py..py+2, cols px..px+2
    float m = xt[3][ctr];
    m = fmaxf(m, xt[3][ctr + 1]);  m = fmaxf(m, xt[3][ctr + 2]);
    m = fmaxf(m, xt[3][ctr + 10]); m = fmaxf(m, xt[3][ctr + 11]);
    m = fmaxf(m, xt[3][ctr + 12]); m = fmaxf(m, xt[3][ctr + 20]);
    m = fmaxf(m, xt[3][ctr + 21]); m = fmaxf(m, xt[3][ctr + 22]);
    plout[P] = m;
  }

  // ---- B: perception from LDS tile (wave q: channels q, q+4, q+8, q+12)
  const int ctr = (1 + py) * 10 + (1 + px);
#pragma unroll
  for (int cc = 0; cc < 4; ++cc) {
    const int c = q + cc * 4;                 // wave-uniform
    const float* xc = &xt[c][0];
    const float v00 = xc[ctr - 11], v01 = xc[ctr - 10], v02 = xc[ctr - 9];
    const float v10 = xc[ctr - 1],  v11 = xc[ctr],      v12 = xc[ctr + 1];
    const float v20 = xc[ctr + 9],  v21 = xc[ctr + 10], v22 = xc[ctr + 11];
    P_LDS(c, lane)          = v11;
    P_LDS(CC + c, lane)     = ((v02 - v00) + 2.f * (v12 - v10) + (v22 - v20)) * 0.125f;
    P_LDS(2 * CC + c, lane) = ((v20 - v00) + 2.f * (v21 - v01) + (v22 - v02)) * 0.125f;
  }
  __syncthreads();

  // ---- B2: per-lane features into registers (STATIC indices only)
  float p[3 * CC];
#pragma unroll
  for (int f = 0; f < 3 * CC; ++f) p[f] = P_LDS(f, lane);

  // ---- C: MLP, 32 hidden rows per wave
  float upd[CC];
#pragma unroll
  for (int k = 0; k < CC; ++k) upd[k] = 0.f;

  const int row0 = q * 32;
#pragma unroll 2
  for (int o = 0; o < 32; ++o) {
    const int row = row0 + o;
    const float* wr = w1 + row * 48;     // wave-uniform -> s_load broadcast
    float a0 = b1[row], a1 = 0.f, a2 = 0.f, a3 = 0.f;
#pragma unroll
    for (int c = 0; c < 12; ++c) {
      a0 = fmaf(wr[c     ], p[c     ], a0);
      a1 = fmaf(wr[c + 12], p[c + 12], a1);
      a2 = fmaf(wr[c + 24], p[c + 24], a2);
      a3 = fmaf(wr[c + 36], p[c + 36], a3);
    }
    float y = (a0 + a1) + (a2 + a3);
    y = fmaxf(y, 0.f);                   // relu
    const float* w2r = w2t + row * CC;   // wave-uniform -> s_load broadcast
#pragma unroll
    for (int k = 0; k < CC; ++k) upd[k] = fmaf(w2r[k], y, upd[k]);
  }

  __syncthreads();                       // p_lds dead -> reuse overlay as red
#pragma unroll
  for (int k = 0; k < CC; ++k) RED(q, k, lane) = upd[k];
  __syncthreads();

  const float fire = fire_lds[lane];
  const int c0 = q * 4;                  // this wave finalizes 4 channels
#pragma unroll
  for (int cc = 0; cc < 4; ++cc) {
    const int c = c0 + cc;
    float s = (RED(0, c, lane) + RED(1, c, lane)) +
              (RED(2, c, lane) + RED(3, c, lane)) + b2[c];
    // center x value from LDS (runtime c ok for LDS, never for reg arrays)
    rawout[b * CHW + c * HW + h * WW + w] = xt[c][ctr] + s * fire;
  }
#undef P_LDS
#undef RED
}

// ---------------- Final kernel: life mask + clip -> output -----------------
// grid 1152 = 8 batches x 144; block = 64 pixels x 4 channel quads.
__global__ __launch_bounds__(256) void ca_life(
    const float* __restrict__ prelife, const float* __restrict__ raw,
    float* __restrict__ xnext)
{
  const int lane = threadIdx.x & 63;
  const int g    = threadIdx.x >> 6;        // channel quad 0..3
  const int b    = blockIdx.x & 7;
  const int seg  = blockIdx.x >> 3;
  const int rem  = seg * 64 + lane;
  const int h = rem / WW;
  const int w = rem - h * WW;
  const int P = b * HW + rem;
  const bool hm = (h > 0), hp = (h < HH - 1), wm = (w > 0), wp = (w < WW - 1);

  float m2;
  {
    const float* xr = raw + b * CHW + 3 * HW + h * WW + w;
    m2 = xr[0];
    if (hm) {
      m2 = fmaxf(m2, xr[-WW]);
      if (wm) m2 = fmaxf(m2, xr[-WW - 1]);
      if (wp) m2 = fmaxf(m2, xr[-WW + 1]);
    }
    if (wm) m2 = fmaxf(m2, xr[-1]);
    if (wp) m2 = fmaxf(m2, xr[ 1]);
    if (hp) {
      m2 = fmaxf(m2, xr[WW]);
      if (wm) m2 = fmaxf(m2, xr[WW - 1]);
      if (wp) m2 = fmaxf(m2, xr[WW + 1]);
    }
  }
  const float life = ((prelife[P] > 0.1f) && (m2 > 0.1f)) ? 1.f : 0.f;

  const int base = b * CHW + h * WW + w;
#pragma unroll
  for (int cc = 0; cc < 4; ++cc) {
    const int c = g + cc * 4;               // wave-uniform
    float v = raw[base + c * HW] * life;
    v = fminf(fmaxf(v, -10.f), 10.f);
    xnext[base + c * HW] = v;
  }
}

// ---------------- launcher ----------------
extern "C" void kernel_launch(void* const* d_in, const int* in_sizes, int n_in,
                              void* d_out, int out_size, void* d_ws, size_t ws_size,
                              hipStream_t stream) {
  const float* x  = (const float*)d_in[0];
  const float* w1 = (const float*)d_in[1];
  const float* b1 = (const float*)d_in[2];
  const float* w2 = (const float*)d_in[3];
  const float* b2 = (const float*)d_in[4];
  float* out = (float*)d_out;

  char* ws = (char*)d_ws;
  const size_t BUF = (size_t)NPIX * CC * sizeof(float);   // 4,718,592 B
  float* rawA = (float*)(ws);
  float* rawB = (float*)(ws + BUF);
  float* w2t  = (float*)(ws + 2 * BUF);                   // 8 KiB
  float* plA  = (float*)(ws + 2 * BUF + 8192);            // NPIX floats
  float* plB  = (float*)(ws + 2 * BUF + 8192 + (size_t)NPIX * 4);

  hipLaunchKernelGGL(transp_w2, dim3(8), dim3(256), 0, stream, w2, w2t);

  for (int i = 0; i < STEPS; ++i) {
    uint32_t ka, kb;
    threefry2x32(0u, 42u, 0u, (uint32_t)i, ka, kb);       // fold_in(key(42), i)
    const float* src = (i == 0) ? x : ((i & 1) ? rawA : rawB);
    const float* plp = (i & 1) ? plA : plB;
    float* ro        = (i & 1) ? rawB : rawA;             // raw_i
    float* po        = (i & 1) ? plB : plA;               // prelife_i
    hipLaunchKernelGGL(ca_fused, dim3(NPIX / 64), dim3(256), 0, stream,
                       src, plp, w1, b1, w2t, b2, ro, po, ka, kb, (i == 0) ? 0 : 1);
  }
  // raw_15 / prelife_15 are in rawB / plB (15 is odd)
  hipLaunchKernelGGL(ca_life, dim3(NPIX / 64), dim3(256), 0, stream,
                     plB, rawB, out);
  (void)in_sizes; (void)n_in; (void)out_size; (void)ws_size;
}